// Round 4
// baseline (1141.902 us; speedup 1.0000x reference)
//
#include <hip/hip_runtime.h>
#include <stdint.h>
#include <math.h>

// Problem constants
#define A_    32
#define C_    8
#define B_    32
#define D_    16
#define KK_   9
#define KKA_  288          // KK * A
#define BD_   512          // B * D
#define HW_   14
#define L_    196          // 14*14
#define NSITES 784         // 4 * 196
#define XROW  (KKA_ * C_)  // 2304 floats per site (im2col row)
#define NKG   18           // kk groups of 16
#define ST    16           // sites per pass-block

// ws layout (floats):
//   X       [NSITES][XROW]        1,806,336 f  (7.2 MB)
//   partial [NKG][NSITES][BD_]    7,225,344 f  (28.9 MB)
//   v_cum   [NSITES][BD_]           401,408 f  (1.6 MB)

// ---------------- im2col: X[site][kk][c] from pose ----------------
__global__ __launch_bounds__(256) void k_im2col(
    const float* __restrict__ pose, float* __restrict__ X)
{
    const int site = blockIdx.x;
    const int b  = site / L_;
    const int l  = site - b * L_;
    const int oh = l / HW_;
    const int ow = l - oh * HW_;
    for (int i = threadIdx.x; i < XROW; i += 256) {
        const int kk = i >> 3, c = i & 7;
        const int p = kk >> 5, a = kk & 31;
        const int y = oh + p / 3 - 1;
        const int x = ow + p % 3 - 1;
        float val = 0.f;
        if (y >= 0 && y < HW_ && x >= 0 && x < HW_) {
            val = pose[(((size_t)b * (A_ * C_) + a * C_ + c) * HW_ + y) * HW_ + x];
        }
        X[(size_t)site * XROW + i] = val;
    }
}

// ---------------- fused pass: recompute po + routing, partial s ----------------
// grid (49, 18), block 256 = 4 waves. Block covers 16 sites x 16 kk.
// Wave w owns kk-in-block = w*4 .. w*4+4; lane ln owns p = ln*8 .. ln*8+8
// (B = ln>>1, D-half = ln&1 -> in-wave softmax, same mapping validated R0/R1).
// v_cum == 0 (pass 1) gives u=0 -> c = 1/32 exactly.
__global__ __launch_bounds__(256, 2) void k_pass(
    const float* __restrict__ X, const float* __restrict__ W,
    const float* __restrict__ v_cum, float* __restrict__ partial)
{
    const int t  = threadIdx.x;
    const int w  = t >> 6;
    const int ln = t & 63;
    const int site0 = blockIdx.x * ST;
    const int kkg   = blockIdx.y;

    __shared__ float x_t[ST][16][C_];   // 8 KB
    __shared__ float v_t[ST][BD_];      // 32 KB
    __shared__ float s_t[ST][BD_];      // 32 KB

    // stage x tile: thread t -> (ss = t>>4, kkl = t&15), 8 contiguous floats
    {
        const int ss = t >> 4, kkl = t & 15;
        const float* xp = X + (size_t)(site0 + ss) * XROW + (size_t)(kkg * 16 + kkl) * C_;
        *((float4*)&x_t[ss][kkl][0]) = ((const float4*)xp)[0];
        *((float4*)&x_t[ss][kkl][4]) = ((const float4*)xp)[1];
    }
    // stage v_cum tile + zero s tile: 32 floats per thread
    {
        const float4* vp = (const float4*)(v_cum + (size_t)site0 * BD_ + (size_t)t * 32);
        float4* vt = (float4*)(&v_t[0][0] + t * 32);
        float4* st = (float4*)(&s_t[0][0] + t * 32);
        #pragma unroll
        for (int i = 0; i < 8; ++i) {
            vt[i] = vp[i];
            st[i] = make_float4(0.f, 0.f, 0.f, 0.f);
        }
    }
    __syncthreads();

    float acc[ST][8];
    #pragma unroll
    for (int s = 0; s < ST; ++s)
        #pragma unroll
        for (int j = 0; j < 8; ++j) acc[s][j] = 0.f;

    for (int kkl = 0; kkl < 4; ++kkl) {
        const int kkb = w * 4 + kkl;
        const int kk  = kkg * 16 + kkb;
        // lane's W slab: W[kk][ln*8 .. +8][0..8] = 64 consecutive floats
        const float4* Wp = (const float4*)(W + (size_t)kk * (BD_ * C_) + (size_t)ln * 64);
        float4 wr[16];
        #pragma unroll
        for (int i = 0; i < 16; ++i) wr[i] = Wp[i];

        #pragma unroll
        for (int s = 0; s < ST; ++s) {
            const float4 xa = *(const float4*)&x_t[s][kkb][0];   // wave-uniform broadcast
            const float4 xb = *(const float4*)&x_t[s][kkb][4];
            float po[8];
            #pragma unroll
            for (int j = 0; j < 8; ++j) {
                const float4 wa = wr[2 * j], wb = wr[2 * j + 1];
                po[j] = wa.x * xa.x + wa.y * xa.y + wa.z * xa.z + wa.w * xa.w
                      + wb.x * xb.x + wb.y * xb.y + wb.z * xb.z + wb.w * xb.w;
            }
            const float4 va = *(const float4*)&v_t[s][ln * 8];
            const float4 vb = *(const float4*)&v_t[s][ln * 8 + 4];
            // u[b] = sum_D v * po ; pair-shfl completes the 16-wide D dot
            float u = po[0] * va.x + po[1] * va.y + po[2] * va.z + po[3] * va.w
                    + po[4] * vb.x + po[5] * vb.y + po[6] * vb.z + po[7] * vb.w;
            u += __shfl_xor(u, 1, 64);
            // softmax over B without max-subtraction (|u| bounded ~2)
            float e = __expf(u);
            float se = e;
            #pragma unroll
            for (int m = 2; m < 64; m <<= 1) se += __shfl_xor(se, m, 64);
            const float c = e * __builtin_amdgcn_rcpf(se);
            #pragma unroll
            for (int j = 0; j < 8; ++j) acc[s][j] += c * po[j];
        }
    }

    // merge 4 waves' partial s into s_t (each (s,p) hit by exactly 4 waves)
    #pragma unroll
    for (int s = 0; s < ST; ++s)
        #pragma unroll
        for (int j = 0; j < 8; ++j)
            atomicAdd(&s_t[s][ln * 8 + j], acc[s][j]);
    __syncthreads();

    // write block's s tile to partial[kkg][site0..+16][:]
    {
        float4* pp = (float4*)(partial + ((size_t)kkg * NSITES + site0) * BD_ + (size_t)t * 32);
        const float4* st = (const float4*)(&s_t[0][0] + t * 32);
        #pragma unroll
        for (int i = 0; i < 8; ++i) pp[i] = st[i];
    }
}

// ---------------- squash: reduce partials, squash, update v_cum / write out ----------------
// grid 196, block 256: wave per site. lane ln owns p = ln*8..+8.
// squash norm is PER OUTPUT CAPSULE B over its D=16 elements: lane pair
// {2B, 2B+1} holds those 16 values -> ONE pair shfl, NOT a 64-lane reduction.
// (R2 bug: full 64-lane msq reduction normalized by the 512-dim norm.)
__global__ __launch_bounds__(256) void k_squash(
    const float* __restrict__ partial, float* __restrict__ v_cum,
    float* __restrict__ out, int pass)
{
    const int w  = threadIdx.x >> 6;
    const int ln = threadIdx.x & 63;
    const int site = blockIdx.x * 4 + w;

    float s8[8];
    #pragma unroll
    for (int j = 0; j < 8; ++j) s8[j] = 0.f;
    const float* pp = partial + (size_t)site * BD_ + (size_t)ln * 8;
    for (int g = 0; g < NKG; ++g) {
        const float4 a = *(const float4*)(pp + (size_t)g * NSITES * BD_);
        const float4 b = *(const float4*)(pp + (size_t)g * NSITES * BD_ + 4);
        s8[0] += a.x; s8[1] += a.y; s8[2] += a.z; s8[3] += a.w;
        s8[4] += b.x; s8[5] += b.y; s8[6] += b.z; s8[7] += b.w;
    }
    float msq = 0.f;
    #pragma unroll
    for (int j = 0; j < 8; ++j) msq += s8[j] * s8[j];
    msq += __shfl_xor(msq, 1, 64);                // pair = other half of this B's D
    const float fac = sqrtf(msq) / (1.f + msq);   // squash: s * |s|/(1+|s|^2)

    if (pass < 2) {
        float* vp = v_cum + (size_t)site * BD_ + (size_t)ln * 8;
        #pragma unroll
        for (int j = 0; j < 8; ++j) {
            const float v = s8[j] * fac;
            vp[j] = (pass == 0) ? v : vp[j] + v;   // v_cum = v1 (+ v2)
        }
    } else {
        // final pass: write v3 transposed -> out[b][bd][l]
        const int b = site / L_;
        const int l = site - b * L_;
        float* op = out + (size_t)b * BD_ * L_ + l;
        #pragma unroll
        for (int j = 0; j < 8; ++j) op[(size_t)(ln * 8 + j) * L_] = s8[j] * fac;
    }
}

extern "C" void kernel_launch(void* const* d_in, const int* in_sizes, int n_in,
                              void* d_out, int out_size, void* d_ws, size_t ws_size,
                              hipStream_t stream) {
    const float* pose = (const float*)d_in[0];
    const float* W    = (const float*)d_in[1];
    float* out        = (float*)d_out;

    float* Xb = (float*)d_ws;                                   // 1,806,336 f
    float* Pb = Xb + (size_t)NSITES * XROW;                     // 7,225,344 f
    float* Vc = Pb + (size_t)NKG * NSITES * BD_;                //   401,408 f
    // total 9,433,088 floats = 37.7 MB << ws_size

    // v_cum = 0 -> pass-1 softmax(0) = 1/32 exactly
    hipMemsetAsync(Vc, 0, (size_t)NSITES * BD_ * sizeof(float), stream);

    k_im2col<<<dim3(NSITES), dim3(256), 0, stream>>>(pose, Xb);

    for (int pass = 0; pass < 3; ++pass) {
        k_pass<<<dim3(NSITES / ST, NKG), dim3(256), 0, stream>>>(Xb, W, Vc, Pb);
        k_squash<<<dim3(NSITES / 4), dim3(256), 0, stream>>>(Pb, Vc, out, pass);
    }
}

// Round 5
// 805.779 us; speedup vs baseline: 1.4171x; 1.4171x over previous
//
#include <hip/hip_runtime.h>
#include <stdint.h>
#include <math.h>

// Problem constants
#define A_    32
#define C_    8
#define B_    32
#define D_    16
#define KK_   9
#define KKA_  288          // KK * A
#define BD_   512          // B * D
#define HW_   14
#define L_    196          // 14*14
#define NSITES 784         // 4 * 196
#define XROW  (KKA_ * C_)  // 2304 floats per site (im2col row)
#define NKG   18           // kk groups of 16
#define ST    8            // sites per pass-block (8: acc fits in regs, no spill)

// ws layout (floats):
//   X       [NSITES][XROW]        1,806,336 f  (7.2 MB)
//   partial [NKG][NSITES][BD_]    7,225,344 f  (28.9 MB)
//   v_cum   [NSITES][BD_]           401,408 f  (1.6 MB)

// ---------------- im2col: X[site][kk][c] from pose ----------------
__global__ __launch_bounds__(256) void k_im2col(
    const float* __restrict__ pose, float* __restrict__ X)
{
    const int site = blockIdx.x;
    const int b  = site / L_;
    const int l  = site - b * L_;
    const int oh = l / HW_;
    const int ow = l - oh * HW_;
    for (int i = threadIdx.x; i < XROW; i += 256) {
        const int kk = i >> 3, c = i & 7;
        const int p = kk >> 5, a = kk & 31;
        const int y = oh + p / 3 - 1;
        const int x = ow + p % 3 - 1;
        float val = 0.f;
        if (y >= 0 && y < HW_ && x >= 0 && x < HW_) {
            val = pose[(((size_t)b * (A_ * C_) + a * C_ + c) * HW_ + y) * HW_ + x];
        }
        X[(size_t)site * XROW + i] = val;
    }
}

// ---------------- fused pass: recompute po + routing, partial s ----------------
// grid (98, 18), block 256 = 4 waves. Block covers 8 sites x 16 kk.
// Wave w owns kk-in-block = w*4 .. w*4+4; lane ln owns p = ln*8 .. ln*8+8
// (B = ln>>1, D-half = ln&1 -> in-wave softmax).
// v_cum == 0 (pass 1) gives u=0 -> c = 1/32 exactly.
// NO __launch_bounds__ min-occupancy: R4's (256,2) clamped VGPRs to 128 and
// spilled ~1KB/thread to scratch (292 MB writes/dispatch). Live state ~190 VGPRs.
__global__ __launch_bounds__(256) void k_pass(
    const float* __restrict__ X, const float* __restrict__ W,
    const float* __restrict__ v_cum, float* __restrict__ partial)
{
    const int t  = threadIdx.x;
    const int w  = t >> 6;
    const int ln = t & 63;
    const int site0 = blockIdx.x * ST;
    const int kkg   = blockIdx.y;

    __shared__ float x_t[ST][16][C_];   // 4 KB
    __shared__ float v_t[ST][BD_];      // 16 KB
    __shared__ float s_t[ST][BD_];      // 16 KB

    // stage x tile: 8 sites x 16 kk x 8 c = 1024 floats, 4 per thread (float4)
    {
        const int f  = t * 4;
        const int ss = f >> 7;
        const int rem = f & 127;            // kkl*8 + c, c in {0,4}
        const float* xp = X + (size_t)(site0 + ss) * XROW + (size_t)kkg * 128 + rem;
        *(float4*)&x_t[ss][rem >> 3][rem & 7] = *(const float4*)xp;
    }
    // stage v_cum tile + zero s tile: 16 floats per thread
    {
        const float4* vp = (const float4*)(v_cum + (size_t)site0 * BD_ + (size_t)t * 16);
        float4* vt = (float4*)(&v_t[0][0] + t * 16);
        float4* st = (float4*)(&s_t[0][0] + t * 16);
        #pragma unroll
        for (int i = 0; i < 4; ++i) {
            vt[i] = vp[i];
            st[i] = make_float4(0.f, 0.f, 0.f, 0.f);
        }
    }
    __syncthreads();

    float acc[ST][8];
    #pragma unroll
    for (int s = 0; s < ST; ++s)
        #pragma unroll
        for (int j = 0; j < 8; ++j) acc[s][j] = 0.f;

    for (int kkl = 0; kkl < 4; ++kkl) {
        const int kkb = w * 4 + kkl;
        const int kk  = kkg * 16 + kkb;
        // lane's W slab: W[kk][ln*8 .. +8][0..8] = 64 consecutive floats
        const float4* Wp = (const float4*)(W + (size_t)kk * (BD_ * C_) + (size_t)ln * 64);
        float4 wr[16];
        #pragma unroll
        for (int i = 0; i < 16; ++i) wr[i] = Wp[i];

        #pragma unroll
        for (int s = 0; s < ST; ++s) {
            const float4 xa = *(const float4*)&x_t[s][kkb][0];   // wave-uniform broadcast
            const float4 xb = *(const float4*)&x_t[s][kkb][4];
            float po[8];
            #pragma unroll
            for (int j = 0; j < 8; ++j) {
                const float4 wa = wr[2 * j], wb = wr[2 * j + 1];
                po[j] = wa.x * xa.x + wa.y * xa.y + wa.z * xa.z + wa.w * xa.w
                      + wb.x * xb.x + wb.y * xb.y + wb.z * xb.z + wb.w * xb.w;
            }
            const float4 va = *(const float4*)&v_t[s][ln * 8];
            const float4 vb = *(const float4*)&v_t[s][ln * 8 + 4];
            // u[b] = sum_D v * po ; pair-shfl completes the 16-wide D dot
            float u = po[0] * va.x + po[1] * va.y + po[2] * va.z + po[3] * va.w
                    + po[4] * vb.x + po[5] * vb.y + po[6] * vb.z + po[7] * vb.w;
            u += __shfl_xor(u, 1, 64);
            // softmax over B without max-subtraction (|u| bounded ~2)
            float e = __expf(u);
            float se = e;
            #pragma unroll
            for (int m = 2; m < 64; m <<= 1) se += __shfl_xor(se, m, 64);
            const float c = e * __builtin_amdgcn_rcpf(se);
            #pragma unroll
            for (int j = 0; j < 8; ++j) acc[s][j] += c * po[j];
        }
    }

    // merge 4 waves' partials into s_t. j staggered by (ln>>2) so the 64 lanes'
    // atomic addresses (ln*8+j) land 2-way per bank instead of 16-way (R4:
    // 4.5M SQ_LDS_BANK_CONFLICT from the unstaggered stride-8 pattern).
    #pragma unroll
    for (int s = 0; s < ST; ++s) {
        #pragma unroll
        for (int jj = 0; jj < 8; ++jj) {
            const int j = (jj + (ln >> 2)) & 7;
            atomicAdd(&s_t[s][ln * 8 + j], acc[s][j]);
        }
    }
    __syncthreads();

    // write block's s tile to partial[kkg][site0..+8][:], 16 floats per thread
    {
        float4* pp = (float4*)(partial + ((size_t)kkg * NSITES + site0) * BD_ + (size_t)t * 16);
        const float4* st = (const float4*)(&s_t[0][0] + t * 16);
        #pragma unroll
        for (int i = 0; i < 4; ++i) pp[i] = st[i];
    }
}

// ---------------- squash: reduce partials, squash, update v_cum / write out ----------------
// grid 196, block 256: wave per site. lane ln owns p = ln*8..+8.
// squash norm is PER OUTPUT CAPSULE B over D=16: lane pair {2B,2B+1} holds it
// -> ONE pair shfl (R2 bug was a full 64-lane reduction).
__global__ __launch_bounds__(256) void k_squash(
    const float* __restrict__ partial, float* __restrict__ v_cum,
    float* __restrict__ out, int pass)
{
    const int w  = threadIdx.x >> 6;
    const int ln = threadIdx.x & 63;
    const int site = blockIdx.x * 4 + w;

    float s8[8];
    #pragma unroll
    for (int j = 0; j < 8; ++j) s8[j] = 0.f;
    const float* pp = partial + (size_t)site * BD_ + (size_t)ln * 8;
    for (int g = 0; g < NKG; ++g) {
        const float4 a = *(const float4*)(pp + (size_t)g * NSITES * BD_);
        const float4 b = *(const float4*)(pp + (size_t)g * NSITES * BD_ + 4);
        s8[0] += a.x; s8[1] += a.y; s8[2] += a.z; s8[3] += a.w;
        s8[4] += b.x; s8[5] += b.y; s8[6] += b.z; s8[7] += b.w;
    }
    float msq = 0.f;
    #pragma unroll
    for (int j = 0; j < 8; ++j) msq += s8[j] * s8[j];
    msq += __shfl_xor(msq, 1, 64);                // pair = other half of this B's D
    const float fac = sqrtf(msq) / (1.f + msq);   // squash: s * |s|/(1+|s|^2)

    if (pass < 2) {
        float* vp = v_cum + (size_t)site * BD_ + (size_t)ln * 8;
        #pragma unroll
        for (int j = 0; j < 8; ++j) {
            const float v = s8[j] * fac;
            vp[j] = (pass == 0) ? v : vp[j] + v;   // v_cum = v1 (+ v2)
        }
    } else {
        // final pass: write v3 transposed -> out[b][bd][l]
        const int b = site / L_;
        const int l = site - b * L_;
        float* op = out + (size_t)b * BD_ * L_ + l;
        #pragma unroll
        for (int j = 0; j < 8; ++j) op[(size_t)(ln * 8 + j) * L_] = s8[j] * fac;
    }
}

extern "C" void kernel_launch(void* const* d_in, const int* in_sizes, int n_in,
                              void* d_out, int out_size, void* d_ws, size_t ws_size,
                              hipStream_t stream) {
    const float* pose = (const float*)d_in[0];
    const float* W    = (const float*)d_in[1];
    float* out        = (float*)d_out;

    float* Xb = (float*)d_ws;                                   // 1,806,336 f
    float* Pb = Xb + (size_t)NSITES * XROW;                     // 7,225,344 f
    float* Vc = Pb + (size_t)NKG * NSITES * BD_;                //   401,408 f
    // total 9,433,088 floats = 37.7 MB << ws_size

    // v_cum = 0 -> pass-1 softmax(0) = 1/32 exactly
    hipMemsetAsync(Vc, 0, (size_t)NSITES * BD_ * sizeof(float), stream);

    k_im2col<<<dim3(NSITES), dim3(256), 0, stream>>>(pose, Xb);

    for (int pass = 0; pass < 3; ++pass) {
        k_pass<<<dim3(NSITES / ST, NKG), dim3(256), 0, stream>>>(Xb, W, Vc, Pb);
        k_squash<<<dim3(NSITES / 4), dim3(256), 0, stream>>>(Pb, Vc, out, pass);
    }
}

// Round 6
// 758.848 us; speedup vs baseline: 1.5048x; 1.0618x over previous
//
#include <hip/hip_runtime.h>
#include <stdint.h>
#include <math.h>

// Problem constants
#define A_    32
#define C_    8
#define B_    32
#define D_    16
#define KK_   9
#define KKA_  288          // KK * A
#define BD_   512          // B * D
#define HW_   14
#define L_    196          // 14*14
#define NSITES 784         // 4 * 196
#define XROW  (KKA_ * C_)  // 2304 floats per site (im2col row)
#define NKG   18           // kk groups of 16
#define ST    8            // sites per pass-block

// ws layout (floats):
//   X       [NSITES][XROW]        1,806,336 f  (7.2 MB)
//   partial [NKG][NSITES][BD_]    7,225,344 f  (28.9 MB)  (site-transposed: j*64+ln)
//   v_cum   [NSITES][BD_]           401,408 f  (1.6 MB)   (canonical)

// ---------------- im2col: X[site][kk][c] from pose ----------------
__global__ __launch_bounds__(256) void k_im2col(
    const float* __restrict__ pose, float* __restrict__ X)
{
    const int site = blockIdx.x;
    const int b  = site / L_;
    const int l  = site - b * L_;
    const int oh = l / HW_;
    const int ow = l - oh * HW_;
    for (int i = threadIdx.x; i < XROW; i += 256) {
        const int kk = i >> 3, c = i & 7;
        const int p = kk >> 5, a = kk & 31;
        const int y = oh + p / 3 - 1;
        const int x = ow + p % 3 - 1;
        float val = 0.f;
        if (y >= 0 && y < HW_ && x >= 0 && x < HW_) {
            val = pose[(((size_t)b * (A_ * C_) + a * C_ + c) * HW_ + y) * HW_ + x];
        }
        X[(size_t)site * XROW + i] = val;
    }
}

// ---------------- fused pass: recompute po + routing, partial s ----------------
// grid (98, 18), block 256 = 4 waves. Block covers 8 sites x 16 kk.
// Wave w owns kk-in-block = w*4 .. w*4+4; lane ln owns p = ln*8 .. ln*8+8
// (B = ln>>1, D-half = ln&1 -> in-wave softmax).
// v_cum == 0 (pass 1) gives u=0 -> c = 1/32 exactly.
//
// CRITICAL (R5 post-mortem): every register-array index (acc, po, wr) must be
// a compile-time constant. R5's runtime j = (jj+(ln>>2))&7 into acc[s][j]
// pushed acc to scratch: 250 MB/dispatch scratch traffic, VALUBusy 10%.
// Bank conflicts are instead fixed by TRANSPOSING s_t: element (s, p=ln*8+jj)
// stored at s_t[s][jj*64+ln] -> for static jj the 64 lanes hit 64 consecutive
// words = 2 lanes/bank (free, m136). partial keeps this transposed layout;
// k_squash un-transposes for free via its read addressing (coalesced).
__global__ __launch_bounds__(256) void k_pass(
    const float* __restrict__ X, const float* __restrict__ W,
    const float* __restrict__ v_cum, float* __restrict__ partial)
{
    const int t  = threadIdx.x;
    const int w  = t >> 6;
    const int ln = t & 63;
    const int site0 = blockIdx.x * ST;
    const int kkg   = blockIdx.y;

    __shared__ float x_t[ST][16][C_];   // 4 KB
    __shared__ float v_t[ST][BD_];      // 16 KB  (canonical: p = ln*8+j)
    __shared__ float s_t[ST][BD_];      // 16 KB  (transposed: jj*64+ln)

    // stage x tile: 8 sites x 16 kk x 8 c = 1024 floats, one float4 per thread
    {
        const int f   = t * 4;
        const int ss  = f >> 7;
        const int rem = f & 127;            // kkl*8 + c, c in {0,4}
        const float* xp = X + (size_t)(site0 + ss) * XROW + (size_t)kkg * 128 + rem;
        *(float4*)&x_t[ss][rem >> 3][rem & 7] = *(const float4*)xp;
    }
    // stage v_cum tile + zero s tile: 16 floats per thread
    {
        const float4* vp = (const float4*)(v_cum + (size_t)site0 * BD_ + (size_t)t * 16);
        float4* vt = (float4*)(&v_t[0][0] + t * 16);
        float4* st = (float4*)(&s_t[0][0] + t * 16);
        #pragma unroll
        for (int i = 0; i < 4; ++i) {
            vt[i] = vp[i];
            st[i] = make_float4(0.f, 0.f, 0.f, 0.f);
        }
    }
    __syncthreads();

    float acc[ST][8];
    #pragma unroll
    for (int s = 0; s < ST; ++s)
        #pragma unroll
        for (int j = 0; j < 8; ++j) acc[s][j] = 0.f;

    for (int kkl = 0; kkl < 4; ++kkl) {
        const int kkb = w * 4 + kkl;
        const int kk  = kkg * 16 + kkb;
        // lane's W slab: W[kk][ln*8 .. +8][0..8] = 64 consecutive floats
        const float4* Wp = (const float4*)(W + (size_t)kk * (BD_ * C_) + (size_t)ln * 64);
        float4 wr[16];
        #pragma unroll
        for (int i = 0; i < 16; ++i) wr[i] = Wp[i];

        #pragma unroll
        for (int s = 0; s < ST; ++s) {
            const float4 xa = *(const float4*)&x_t[s][kkb][0];   // wave-uniform broadcast
            const float4 xb = *(const float4*)&x_t[s][kkb][4];
            float po[8];
            #pragma unroll
            for (int j = 0; j < 8; ++j) {
                const float4 wa = wr[2 * j], wb = wr[2 * j + 1];
                po[j] = wa.x * xa.x + wa.y * xa.y + wa.z * xa.z + wa.w * xa.w
                      + wb.x * xb.x + wb.y * xb.y + wb.z * xb.z + wb.w * xb.w;
            }
            const float4 va = *(const float4*)&v_t[s][ln * 8];
            const float4 vb = *(const float4*)&v_t[s][ln * 8 + 4];
            // u[b] = sum_D v * po ; pair-shfl completes the 16-wide D dot
            float u = po[0] * va.x + po[1] * va.y + po[2] * va.z + po[3] * va.w
                    + po[4] * vb.x + po[5] * vb.y + po[6] * vb.z + po[7] * vb.w;
            u += __shfl_xor(u, 1, 64);
            // softmax over B without max-subtraction (|u| bounded ~2)
            float e = __expf(u);
            float se = e;
            #pragma unroll
            for (int m = 2; m < 64; m <<= 1) se += __shfl_xor(se, m, 64);
            const float c = e * __builtin_amdgcn_rcpf(se);
            #pragma unroll
            for (int j = 0; j < 8; ++j) acc[s][j] += c * po[j];
        }
    }

    // merge 4 waves into transposed s_t: static register index, conflict-free banks
    #pragma unroll
    for (int s = 0; s < ST; ++s) {
        #pragma unroll
        for (int jj = 0; jj < 8; ++jj) {
            atomicAdd(&s_t[s][jj * 64 + ln], acc[s][jj]);
        }
    }
    __syncthreads();

    // write block's s tile (transposed layout, verbatim) to partial
    {
        float4* pp = (float4*)(partial + ((size_t)kkg * NSITES + site0) * BD_ + (size_t)t * 16);
        const float4* st = (const float4*)(&s_t[0][0] + t * 16);
        #pragma unroll
        for (int i = 0; i < 4; ++i) pp[i] = st[i];
    }
}

// ---------------- squash: reduce partials, squash, update v_cum / write out ----------------
// grid 196, block 256: wave per site. lane ln owns p = ln*8..+8 (canonical).
// partial is site-transposed (element p=ln*8+j at offset j*64+ln): for fixed j
// the 64 lanes read 64 consecutive dwords -> coalesced.
// squash norm is PER OUTPUT CAPSULE B over D=16: lane pair {2B,2B+1} -> ONE pair shfl.
__global__ __launch_bounds__(256) void k_squash(
    const float* __restrict__ partial, float* __restrict__ v_cum,
    float* __restrict__ out, int pass)
{
    const int w  = threadIdx.x >> 6;
    const int ln = threadIdx.x & 63;
    const int site = blockIdx.x * 4 + w;

    float s8[8];
    #pragma unroll
    for (int j = 0; j < 8; ++j) s8[j] = 0.f;
    const float* pp = partial + (size_t)site * BD_ + ln;
    for (int g = 0; g < NKG; ++g) {
        const float* q = pp + (size_t)g * NSITES * BD_;
        #pragma unroll
        for (int j = 0; j < 8; ++j) s8[j] += q[j * 64];
    }
    float msq = 0.f;
    #pragma unroll
    for (int j = 0; j < 8; ++j) msq += s8[j] * s8[j];
    msq += __shfl_xor(msq, 1, 64);                // pair = other half of this B's D
    const float fac = sqrtf(msq) / (1.f + msq);   // squash: s * |s|/(1+|s|^2)

    if (pass < 2) {
        float* vp = v_cum + (size_t)site * BD_ + (size_t)ln * 8;
        #pragma unroll
        for (int j = 0; j < 8; ++j) {
            const float v = s8[j] * fac;
            vp[j] = (pass == 0) ? v : vp[j] + v;   // v_cum = v1 (+ v2)
        }
    } else {
        // final pass: write v3 transposed -> out[b][bd][l]
        const int b = site / L_;
        const int l = site - b * L_;
        float* op = out + (size_t)b * BD_ * L_ + l;
        #pragma unroll
        for (int j = 0; j < 8; ++j) op[(size_t)(ln * 8 + j) * L_] = s8[j] * fac;
    }
}

extern "C" void kernel_launch(void* const* d_in, const int* in_sizes, int n_in,
                              void* d_out, int out_size, void* d_ws, size_t ws_size,
                              hipStream_t stream) {
    const float* pose = (const float*)d_in[0];
    const float* W    = (const float*)d_in[1];
    float* out        = (float*)d_out;

    float* Xb = (float*)d_ws;                                   // 1,806,336 f
    float* Pb = Xb + (size_t)NSITES * XROW;                     // 7,225,344 f
    float* Vc = Pb + (size_t)NKG * NSITES * BD_;                //   401,408 f
    // total 9,433,088 floats = 37.7 MB << ws_size

    // v_cum = 0 -> pass-1 softmax(0) = 1/32 exactly
    hipMemsetAsync(Vc, 0, (size_t)NSITES * BD_ * sizeof(float), stream);

    k_im2col<<<dim3(NSITES), dim3(256), 0, stream>>>(pose, Xb);

    for (int pass = 0; pass < 3; ++pass) {
        k_pass<<<dim3(NSITES / ST, NKG), dim3(256), 0, stream>>>(Xb, W, Vc, Pb);
        k_squash<<<dim3(NSITES / 4), dim3(256), 0, stream>>>(Pb, Vc, out, pass);
    }
}